// Round 1
// baseline (523.550 us; speedup 1.0000x reference)
//
#include <hip/hip_runtime.h>
#include <hip/hip_bf16.h>

// Shapes: B=16, C=256, H=64, W=64, HW=4096, per-batch plane = 256*4096 floats.
// Pipeline:
//   h   = relu(bn1(pre_w · x))            -> ws (h buffer)
//   s   = combined_dw9(h) + bias_sum      -> d_out (temp)
//   t   = relu(bn2(pw_w · s))             -> ws (h buffer, h dead)
//   out = relu(bn3(post_w · t))           -> d_out (s dead)

#define HW 4096
#define CCH 256

// ---------------------------------------------------------------------------
// Tiny kernel: combine dw3/5/7/9 into one 9x9 kernel (+identity at center),
// and sum the four biases.
__global__ void combine_w_kernel(const float* __restrict__ w3, const float* __restrict__ b3,
                                 const float* __restrict__ w5, const float* __restrict__ b5,
                                 const float* __restrict__ w7, const float* __restrict__ b7,
                                 const float* __restrict__ w9, const float* __restrict__ b9,
                                 float* __restrict__ Wc, float* __restrict__ biasc) {
    int c = blockIdx.x;      // 0..255
    int t = threadIdx.x;     // 0..80
    int dy = t / 9, dx = t % 9;
    float v = w9[c * 81 + t];
    if (dy >= 1 && dy <= 7 && dx >= 1 && dx <= 7) v += w7[c * 49 + (dy - 1) * 7 + (dx - 1)];
    if (dy >= 2 && dy <= 6 && dx >= 2 && dx <= 6) v += w5[c * 25 + (dy - 2) * 5 + (dx - 2)];
    if (dy >= 3 && dy <= 5 && dx >= 3 && dx <= 5) v += w3[c * 9 + (dy - 3) * 3 + (dx - 3)];
    if (dy == 4 && dx == 4) v += 1.0f;   // identity branch
    Wc[c * 81 + t] = v;
    if (t == 0) biasc[c] = b3[c] + b5[c] + b7[c] + b9[c];
}

// ---------------------------------------------------------------------------
// fp32 1x1 conv (batched GEMM) + BN + ReLU.
// Tile: 128 (cout) x 128 (pixels), K-chunks of 16. 256 threads, 8x8 per thread.
__global__ __launch_bounds__(256) void conv1x1_bn_relu(
    const float* __restrict__ in,   // [B][256][4096]
    const float* __restrict__ w,    // [256][256]
    const float* __restrict__ g, const float* __restrict__ bb,
    const float* __restrict__ bm, const float* __restrict__ bv,
    float* __restrict__ out)        // [B][256][4096]
{
    const int b   = blockIdx.z;
    const int co0 = blockIdx.y * 128;
    const int p0  = blockIdx.x * 128;
    const int tid = threadIdx.x;
    const int tx = tid & 15, ty = tid >> 4;
    const int m0 = ty * 8, n0 = tx * 8;

    __shared__ float As[16][128];   // [k][m]
    __shared__ float Bs[16][128];   // [k][n]

    const float* inb  = in  + (size_t)b * (CCH * HW);
    float*       outb = out + (size_t)b * (CCH * HW);

    float acc[8][8];
#pragma unroll
    for (int i = 0; i < 8; i++)
#pragma unroll
        for (int j = 0; j < 8; j++) acc[i][j] = 0.f;

    const int am = tid >> 1;          // 0..127 (m index for A load)
    const int ak = (tid & 1) * 8;     // 0 or 8 (k offset for A load)
    const int br = tid >> 4;          // 0..15  (k index for B load)
    const int bc = (tid & 15) * 8;    // 0..120 (n offset for B load)

    for (int kt = 0; kt < CCH; kt += 16) {
        float4 a0 = *(const float4*)&w[(co0 + am) * CCH + kt + ak];
        float4 a1 = *(const float4*)&w[(co0 + am) * CCH + kt + ak + 4];
        float4 b0 = *(const float4*)&inb[(size_t)(kt + br) * HW + p0 + bc];
        float4 b1 = *(const float4*)&inb[(size_t)(kt + br) * HW + p0 + bc + 4];
        __syncthreads();   // previous tile's compute done
        As[ak + 0][am] = a0.x; As[ak + 1][am] = a0.y;
        As[ak + 2][am] = a0.z; As[ak + 3][am] = a0.w;
        As[ak + 4][am] = a1.x; As[ak + 5][am] = a1.y;
        As[ak + 6][am] = a1.z; As[ak + 7][am] = a1.w;
        *(float4*)&Bs[br][bc]     = b0;
        *(float4*)&Bs[br][bc + 4] = b1;
        __syncthreads();   // tiles ready
#pragma unroll
        for (int kk = 0; kk < 16; kk++) {
            float4 a01 = *(const float4*)&As[kk][m0];
            float4 a23 = *(const float4*)&As[kk][m0 + 4];
            float4 b01 = *(const float4*)&Bs[kk][n0];
            float4 b23 = *(const float4*)&Bs[kk][n0 + 4];
            float av[8] = {a01.x, a01.y, a01.z, a01.w, a23.x, a23.y, a23.z, a23.w};
            float bvv[8] = {b01.x, b01.y, b01.z, b01.w, b23.x, b23.y, b23.z, b23.w};
#pragma unroll
            for (int i = 0; i < 8; i++)
#pragma unroll
                for (int j = 0; j < 8; j++) acc[i][j] = fmaf(av[i], bvv[j], acc[i][j]);
        }
    }

    // fused BN + ReLU epilogue
#pragma unroll
    for (int i = 0; i < 8; i++) {
        int co = co0 + m0 + i;
        float sc = g[co] * rsqrtf(bv[co] + 1e-5f);
        float sh = bb[co] - bm[co] * sc;
        float4 o0, o1;
        o0.x = fmaxf(fmaf(acc[i][0], sc, sh), 0.f);
        o0.y = fmaxf(fmaf(acc[i][1], sc, sh), 0.f);
        o0.z = fmaxf(fmaf(acc[i][2], sc, sh), 0.f);
        o0.w = fmaxf(fmaf(acc[i][3], sc, sh), 0.f);
        o1.x = fmaxf(fmaf(acc[i][4], sc, sh), 0.f);
        o1.y = fmaxf(fmaf(acc[i][5], sc, sh), 0.f);
        o1.z = fmaxf(fmaf(acc[i][6], sc, sh), 0.f);
        o1.w = fmaxf(fmaf(acc[i][7], sc, sh), 0.f);
        *(float4*)&outb[(size_t)co * HW + p0 + n0]     = o0;
        *(float4*)&outb[(size_t)co * HW + p0 + n0 + 4] = o1;
    }
}

// ---------------------------------------------------------------------------
// Combined 9x9 depthwise conv (+identity via center weight, +summed bias).
// One block per (b,c) 64x64 plane; 72x72 halo tile in LDS; each thread does a
// 4x4 micro-tile with float4 row-window loads.
__global__ __launch_bounds__(256) void dw_sum_kernel(
    const float* __restrict__ h,      // [B*256][64][64]
    const float* __restrict__ Wc,     // [256][81]
    const float* __restrict__ biasc,  // [256]
    float* __restrict__ out)          // [B*256][64][64]
{
    const int bcp = blockIdx.x;          // 0..4095 (b*256+c)
    const int c = bcp & 255;
    const size_t plane = (size_t)bcp * HW;
    __shared__ float tile[72 * 72];      // stride 72 keeps 16B alignment
    const int tid = threadIdx.x;

    for (int idx = tid; idx < 72 * 72; idx += 256) {
        int r = idx / 72, cl = idx - r * 72;
        int gy = r - 4, gx = cl - 4;
        float v = 0.f;
        if ((unsigned)gy < 64u && (unsigned)gx < 64u) v = h[plane + gy * 64 + gx];
        tile[idx] = v;
    }
    __syncthreads();

    const int tx = tid & 15, ty = tid >> 4;
    const int x0 = tx * 4, y0 = ty * 4;
    float acc[4][4];
#pragma unroll
    for (int i = 0; i < 4; i++)
#pragma unroll
        for (int j = 0; j < 4; j++) acc[i][j] = 0.f;

    const float* wc = Wc + c * 81;
#pragma unroll
    for (int dy = 0; dy < 9; dy++) {
        float wr[9];
#pragma unroll
        for (int t = 0; t < 9; t++) wr[t] = wc[dy * 9 + t];
#pragma unroll
        for (int yy = 0; yy < 4; yy++) {
            const float* row = &tile[(y0 + yy + dy) * 72 + x0];
            float win[12];
            *(float4*)&win[0] = *(const float4*)&row[0];
            *(float4*)&win[4] = *(const float4*)&row[4];
            *(float4*)&win[8] = *(const float4*)&row[8];
#pragma unroll
            for (int j = 0; j < 4; j++)
#pragma unroll
                for (int t = 0; t < 9; t++)
                    acc[yy][j] = fmaf(wr[t], win[j + t], acc[yy][j]);
        }
    }
    const float bsum = biasc[c];
#pragma unroll
    for (int yy = 0; yy < 4; yy++) {
        float4 o;
        o.x = acc[yy][0] + bsum; o.y = acc[yy][1] + bsum;
        o.z = acc[yy][2] + bsum; o.w = acc[yy][3] + bsum;
        *(float4*)&out[plane + (y0 + yy) * 64 + x0] = o;
    }
}

// ---------------------------------------------------------------------------
extern "C" void kernel_launch(void* const* d_in, const int* in_sizes, int n_in,
                              void* d_out, int out_size, void* d_ws, size_t ws_size,
                              hipStream_t stream) {
    const float* x     = (const float*)d_in[0];
    const float* pre_w = (const float*)d_in[1];
    const float* bn1g  = (const float*)d_in[2];
    const float* bn1b  = (const float*)d_in[3];
    const float* bn1m  = (const float*)d_in[4];
    const float* bn1v  = (const float*)d_in[5];
    const float* dw3w  = (const float*)d_in[6];
    const float* dw3b  = (const float*)d_in[7];
    const float* dw5w  = (const float*)d_in[8];
    const float* dw5b  = (const float*)d_in[9];
    const float* dw7w  = (const float*)d_in[10];
    const float* dw7b  = (const float*)d_in[11];
    const float* dw9w  = (const float*)d_in[12];
    const float* dw9b  = (const float*)d_in[13];
    const float* pww   = (const float*)d_in[14];
    const float* bn2g  = (const float*)d_in[15];
    const float* bn2b  = (const float*)d_in[16];
    const float* bn2m  = (const float*)d_in[17];
    const float* bn2v  = (const float*)d_in[18];
    const float* postw = (const float*)d_in[19];
    const float* bn3g  = (const float*)d_in[20];
    const float* bn3b  = (const float*)d_in[21];
    const float* bn3m  = (const float*)d_in[22];
    const float* bn3v  = (const float*)d_in[23];

    float* hbuf  = (float*)d_ws;                 // 16*256*4096 floats = 64 MiB
    float* Wc    = hbuf + (size_t)16 * CCH * HW;
    float* biasc = Wc + 256 * 81;
    float* outf  = (float*)d_out;

    combine_w_kernel<<<256, 81, 0, stream>>>(dw3w, dw3b, dw5w, dw5b,
                                             dw7w, dw7b, dw9w, dw9b, Wc, biasc);

    dim3 gg(HW / 128, CCH / 128, 16), gb(256);
    // h = relu(bn1(pre_w · x)) -> ws
    conv1x1_bn_relu<<<gg, gb, 0, stream>>>(x, pre_w, bn1g, bn1b, bn1m, bn1v, hbuf);
    // s = combined dw9(h) -> d_out (temp)
    dw_sum_kernel<<<16 * CCH, 256, 0, stream>>>(hbuf, Wc, biasc, outf);
    // t = relu(bn2(pw_w · s)) -> ws (h dead)
    conv1x1_bn_relu<<<gg, gb, 0, stream>>>(outf, pww, bn2g, bn2b, bn2m, bn2v, hbuf);
    // out = relu(bn3(post_w · t)) -> d_out (s dead)
    conv1x1_bn_relu<<<gg, gb, 0, stream>>>(hbuf, postw, bn3g, bn3b, bn3m, bn3v, outf);
}

// Round 2
// 400.187 us; speedup vs baseline: 1.3083x; 1.3083x over previous
//
#include <hip/hip_runtime.h>
#include <stdint.h>

#define HW 4096
#define CCH 256
#define BPL (CCH * HW)   // per-batch plane elems

typedef __attribute__((ext_vector_type(8))) short short8;
typedef __attribute__((ext_vector_type(4))) float floatx4;

__device__ inline unsigned short f2bf(float f) {
    union { float f; unsigned int u; } v; v.f = f;
    unsigned int r = v.u + 0x7FFFu + ((v.u >> 16) & 1u);   // RNE
    return (unsigned short)(r >> 16);
}
__device__ inline float bf2f(unsigned short u) {
    union { unsigned int u; float f; } v; v.u = ((unsigned int)u) << 16;
    return v.f;
}

// ---------------------------------------------------------------------------
// prep: convert 3 weight matrices to bf16, combine dw kernels, fold BN params.
__global__ void prep_kernel(
    const float* __restrict__ pre_w, const float* __restrict__ pw_w, const float* __restrict__ post_w,
    const float* __restrict__ g1, const float* __restrict__ b1, const float* __restrict__ m1, const float* __restrict__ v1,
    const float* __restrict__ g2, const float* __restrict__ b2, const float* __restrict__ m2, const float* __restrict__ v2,
    const float* __restrict__ g3, const float* __restrict__ b3, const float* __restrict__ m3, const float* __restrict__ v3,
    const float* __restrict__ w3d, const float* __restrict__ b3d,
    const float* __restrict__ w5d, const float* __restrict__ b5d,
    const float* __restrict__ w7d, const float* __restrict__ b7d,
    const float* __restrict__ w9d, const float* __restrict__ b9d,
    unsigned short* __restrict__ w1b, unsigned short* __restrict__ w2b, unsigned short* __restrict__ w3b,
    float* __restrict__ Wc, float* __restrict__ biasc,
    float* __restrict__ sc1, float* __restrict__ sh1,
    float* __restrict__ sc2, float* __restrict__ sh2,
    float* __restrict__ sc3, float* __restrict__ sh3)
{
    int c = blockIdx.x, t = threadIdx.x;
    w1b[c * 256 + t] = f2bf(pre_w[c * 256 + t]);
    w2b[c * 256 + t] = f2bf(pw_w[c * 256 + t]);
    w3b[c * 256 + t] = f2bf(post_w[c * 256 + t]);
    if (t < 81) {
        int dy = t / 9, dx = t % 9;
        float v = w9d[c * 81 + t];
        if (dy >= 1 && dy <= 7 && dx >= 1 && dx <= 7) v += w7d[c * 49 + (dy - 1) * 7 + (dx - 1)];
        if (dy >= 2 && dy <= 6 && dx >= 2 && dx <= 6) v += w5d[c * 25 + (dy - 2) * 5 + (dx - 2)];
        if (dy >= 3 && dy <= 5 && dx >= 3 && dx <= 5) v += w3d[c * 9 + (dy - 3) * 3 + (dx - 3)];
        if (dy == 4 && dx == 4) v += 1.0f;   // identity branch
        Wc[c * 81 + t] = v;
    }
    if (t == 81) biasc[c] = b3d[c] + b5d[c] + b7d[c] + b9d[c];
    if (t == 82) { float s = g1[c] * rsqrtf(v1[c] + 1e-5f); sc1[c] = s; sh1[c] = b1[c] - m1[c] * s; }
    if (t == 83) { float s = g2[c] * rsqrtf(v2[c] + 1e-5f); sc2[c] = s; sh2[c] = b2[c] - m2[c] * s; }
    if (t == 84) { float s = g3[c] * rsqrtf(v3[c] + 1e-5f); sc3[c] = s; sh3[c] = b3[c] - m3[c] * s; }
}

// ---------------------------------------------------------------------------
// bf16 MFMA 1x1 conv + BN + ReLU.  NCHW layout.
// A = weights [cout][c] bf16 (k-contiguous).  B = acts [c][p] (transposed into
// LDS Bs[n][k] during staging via pixel-coalesced scalar loads).
// Tile 128(cout) x 128(pix) x BK=32; 4 waves, each 64x64 (4x4 MFMA tiles).
template <typename InT, bool OUT_BF16>
__global__ __launch_bounds__(256) void conv1x1_mfma(
    const InT* __restrict__ in, const unsigned short* __restrict__ wb,
    const float* __restrict__ sc, const float* __restrict__ sh,
    void* __restrict__ outp)
{
    const int b = blockIdx.z, co0 = blockIdx.y * 128, p0 = blockIdx.x * 128;
    const int tid = threadIdx.x;
    const int wave = tid >> 6, lane = tid & 63, quad = lane >> 4, L = lane & 15;
    const int wm = (wave >> 1) * 64, wn = (wave & 1) * 64;

    __shared__ unsigned short As[128 * 40];   // [m][k], row stride 40 (pad)
    __shared__ unsigned short Bs[128 * 40];   // [n][k]

    const InT* inb = in + (size_t)b * BPL;

    floatx4 acc[4][4];
#pragma unroll
    for (int mt = 0; mt < 4; mt++)
#pragma unroll
        for (int nt = 0; nt < 4; nt++) acc[mt][nt] = (floatx4){0.f, 0.f, 0.f, 0.f};

    const int am = tid >> 1, ak = (tid & 1) * 16;   // A: row am, 16 k's at ak
    const int bn = tid >> 1, bk = (tid & 1) * 16;   // B: pixel bn, 16 k's at bk

    for (int kt = 0; kt < CCH; kt += 32) {
        // ---- prefetch to registers ----
        uint4 a0 = *(const uint4*)&wb[(co0 + am) * CCH + kt + ak];
        uint4 a1 = *(const uint4*)&wb[(co0 + am) * CCH + kt + ak + 8];
        unsigned int bp[8];
#pragma unroll
        for (int a = 0; a < 8; a++) {
            unsigned short u0, u1;
            if constexpr (__is_same(InT, float)) {
                u0 = f2bf(inb[(size_t)(kt + bk + 2 * a) * HW + p0 + bn]);
                u1 = f2bf(inb[(size_t)(kt + bk + 2 * a + 1) * HW + p0 + bn]);
            } else {
                u0 = inb[(size_t)(kt + bk + 2 * a) * HW + p0 + bn];
                u1 = inb[(size_t)(kt + bk + 2 * a + 1) * HW + p0 + bn];
            }
            bp[a] = (unsigned int)u0 | ((unsigned int)u1 << 16);
        }
        __syncthreads();   // previous tile fully consumed
        *(uint4*)&As[am * 40 + ak]     = a0;
        *(uint4*)&As[am * 40 + ak + 8] = a1;
        *(uint4*)&Bs[bn * 40 + bk]     = make_uint4(bp[0], bp[1], bp[2], bp[3]);
        *(uint4*)&Bs[bn * 40 + bk + 8] = make_uint4(bp[4], bp[5], bp[6], bp[7]);
        __syncthreads();   // tiles ready
        // ---- fragments + MFMA ----
        short8 af[4], bf[4];
#pragma unroll
        for (int mt = 0; mt < 4; mt++)
            af[mt] = *(const short8*)&As[(wm + mt * 16 + L) * 40 + quad * 8];
#pragma unroll
        for (int nt = 0; nt < 4; nt++)
            bf[nt] = *(const short8*)&Bs[(wn + nt * 16 + L) * 40 + quad * 8];
#pragma unroll
        for (int mt = 0; mt < 4; mt++)
#pragma unroll
            for (int nt = 0; nt < 4; nt++)
                acc[mt][nt] = __builtin_amdgcn_mfma_f32_16x16x32_bf16(
                    af[mt], bf[nt], acc[mt][nt], 0, 0, 0);
    }

    // ---- epilogue: BN + ReLU, store NCHW ----
#pragma unroll
    for (int mt = 0; mt < 4; mt++) {
#pragma unroll
        for (int r = 0; r < 4; r++) {
            const int cout = co0 + wm + mt * 16 + quad * 4 + r;
            const float s = sc[cout], h0 = sh[cout];
#pragma unroll
            for (int nt = 0; nt < 4; nt++) {
                const int pix = p0 + wn + nt * 16 + L;
                float v = fmaxf(fmaf(acc[mt][nt][r], s, h0), 0.f);
                if constexpr (OUT_BF16)
                    ((unsigned short*)outp)[(size_t)b * BPL + (size_t)cout * HW + pix] = f2bf(v);
                else
                    ((float*)outp)[(size_t)b * BPL + (size_t)cout * HW + pix] = v;
            }
        }
    }
}

// ---------------------------------------------------------------------------
// Combined 9x9 depthwise (+identity center, +summed bias), bf16 in/out.
// One block per (b,c) plane; fp32 72x72 LDS tile; per-thread 4x4 outputs with
// row-register reuse (13 row-window loads instead of 36).
__global__ __launch_bounds__(256) void dw_kernel(
    const unsigned short* __restrict__ h, const float* __restrict__ Wc,
    const float* __restrict__ biasc, unsigned short* __restrict__ out)
{
    const int bcp = blockIdx.x, c = bcp & 255;
    const size_t plane = (size_t)bcp * HW;
    __shared__ float tile[72 * 72];
    __shared__ float wcs[81];
    __shared__ float bsh;
    const int tid = threadIdx.x;

    if (tid < 81) wcs[tid] = Wc[c * 81 + tid];
    if (tid == 81) bsh = biasc[c];
    for (int idx = tid; idx < 72 * 72; idx += 256) {
        int r = idx / 72, cl = idx - r * 72;
        int gy = r - 4, gx = cl - 4;
        float v = 0.f;
        if ((unsigned)gy < 64u && (unsigned)gx < 64u) v = bf2f(h[plane + gy * 64 + gx]);
        tile[idx] = v;
    }
    __syncthreads();

    float w[81];
#pragma unroll
    for (int i = 0; i < 81; i++) w[i] = wcs[i];

    const int tx = tid & 15, ty = tid >> 4;
    const int x0 = tx * 4, y0 = ty * 4;
    float acc[4][4];
#pragma unroll
    for (int i = 0; i < 4; i++)
#pragma unroll
        for (int j = 0; j < 4; j++) acc[i][j] = 0.f;

#pragma unroll
    for (int r = 0; r < 13; r++) {
        const float* row = &tile[(y0 + r) * 72 + x0];
        float win[12];
        *(float4*)&win[0] = *(const float4*)&row[0];
        *(float4*)&win[4] = *(const float4*)&row[4];
        *(float4*)&win[8] = *(const float4*)&row[8];
#pragma unroll
        for (int yy = 0; yy < 4; yy++) {
            const int dy = r - yy;
            if (dy >= 0 && dy < 9) {
#pragma unroll
                for (int t2 = 0; t2 < 9; t2++)
#pragma unroll
                    for (int j = 0; j < 4; j++)
                        acc[yy][j] = fmaf(w[dy * 9 + t2], win[j + t2], acc[yy][j]);
            }
        }
    }
    const float bb = bsh;
#pragma unroll
    for (int yy = 0; yy < 4; yy++) {
        ushort4 o;
        o.x = f2bf(acc[yy][0] + bb);
        o.y = f2bf(acc[yy][1] + bb);
        o.z = f2bf(acc[yy][2] + bb);
        o.w = f2bf(acc[yy][3] + bb);
        *(ushort4*)&out[plane + (size_t)(y0 + yy) * 64 + x0] = o;
    }
}

// ---------------------------------------------------------------------------
extern "C" void kernel_launch(void* const* d_in, const int* in_sizes, int n_in,
                              void* d_out, int out_size, void* d_ws, size_t ws_size,
                              hipStream_t stream) {
    const float* x     = (const float*)d_in[0];
    const float* pre_w = (const float*)d_in[1];
    const float* bn1g  = (const float*)d_in[2];
    const float* bn1b  = (const float*)d_in[3];
    const float* bn1m  = (const float*)d_in[4];
    const float* bn1v  = (const float*)d_in[5];
    const float* dw3w  = (const float*)d_in[6];
    const float* dw3b  = (const float*)d_in[7];
    const float* dw5w  = (const float*)d_in[8];
    const float* dw5b  = (const float*)d_in[9];
    const float* dw7w  = (const float*)d_in[10];
    const float* dw7b  = (const float*)d_in[11];
    const float* dw9w  = (const float*)d_in[12];
    const float* dw9b  = (const float*)d_in[13];
    const float* pww   = (const float*)d_in[14];
    const float* bn2g  = (const float*)d_in[15];
    const float* bn2b  = (const float*)d_in[16];
    const float* bn2m  = (const float*)d_in[17];
    const float* bn2v  = (const float*)d_in[18];
    const float* postw = (const float*)d_in[19];
    const float* bn3g  = (const float*)d_in[20];
    const float* bn3b  = (const float*)d_in[21];
    const float* bn3m  = (const float*)d_in[22];
    const float* bn3v  = (const float*)d_in[23];

    // ws layout (bytes):
    //   [0, 32MB)  : bf16 activation buffer (h, then t)
    //   [32MB...)  : w1b/w2b/w3b bf16, Wc, biasc, BN scale/shift
    char* wsb = (char*)d_ws;
    unsigned short* hbuf = (unsigned short*)wsb;                       // 16*256*4096 bf16 = 32 MiB
    char* aux = wsb + (size_t)16 * BPL * 2;
    unsigned short* w1b = (unsigned short*)aux;                        // 128 KiB
    unsigned short* w2b = w1b + 65536;
    unsigned short* w3b = w2b + 65536;
    float* Wc    = (float*)(w3b + 65536);                              // 81*256 fp32
    float* biasc = Wc + 81 * 256;
    float* sc1 = biasc + 256;  float* sh1 = sc1 + 256;
    float* sc2 = sh1 + 256;    float* sh2 = sc2 + 256;
    float* sc3 = sh2 + 256;    float* sh3 = sc3 + 256;

    prep_kernel<<<256, 256, 0, stream>>>(
        pre_w, pww, postw,
        bn1g, bn1b, bn1m, bn1v, bn2g, bn2b, bn2m, bn2v, bn3g, bn3b, bn3m, bn3v,
        dw3w, dw3b, dw5w, dw5b, dw7w, dw7b, dw9w, dw9b,
        w1b, w2b, w3b, Wc, biasc, sc1, sh1, sc2, sh2, sc3, sh3);

    dim3 gg(HW / 128, CCH / 128, 16), gb(256);
    // h = relu(bn1(pre_w · x))  : fp32 in -> bf16 out (ws)
    conv1x1_mfma<float, true><<<gg, gb, 0, stream>>>(x, w1b, sc1, sh1, hbuf);
    // s = dw9(h) + bias        : bf16 -> bf16, parked in d_out's storage
    dw_kernel<<<16 * CCH, 256, 0, stream>>>(hbuf, Wc, biasc, (unsigned short*)d_out);
    // t = relu(bn2(pw_w · s))  : bf16 -> bf16 (ws, h dead)
    conv1x1_mfma<unsigned short, true><<<gg, gb, 0, stream>>>(
        (const unsigned short*)d_out, w2b, sc2, sh2, hbuf);
    // out = relu(bn3(post_w · t)) : bf16 -> fp32 (d_out, s dead)
    conv1x1_mfma<unsigned short, false><<<gg, gb, 0, stream>>>(
        hbuf, w3b, sc3, sh3, (float*)d_out);
}

// Round 4
// 399.033 us; speedup vs baseline: 1.3120x; 1.0029x over previous
//
#include <hip/hip_runtime.h>
#include <stdint.h>

#define HW 4096
#define CCH 256
#define BPL (CCH * HW)          // per-batch plane elems
#define NPX (16 * HW)           // total pixels = 65536

typedef __attribute__((ext_vector_type(8))) short short8;
typedef __attribute__((ext_vector_type(4))) float floatx4;
typedef unsigned short ushort_t;

__device__ inline ushort_t f2bf(float f) {
    union { float f; unsigned int u; } v; v.f = f;
    unsigned int r = v.u + 0x7FFFu + ((v.u >> 16) & 1u);   // RNE
    return (ushort_t)(r >> 16);
}
__device__ inline float bf2f(ushort_t u) {
    union { unsigned int u; float f; } v; v.u = ((unsigned int)u) << 16;
    return v.f;
}

// ---------------------------------------------------------------------------
// prep: weights->bf16, combined dw 9x9 (chunked layout), folded BN params.
// WcP[c][128]: slots 0..44 = dy 0..4 (d*9+dx), slots 64..99 = dy 5..8.
__global__ void prep_kernel(
    const float* __restrict__ pre_w, const float* __restrict__ pw_w, const float* __restrict__ post_w,
    const float* __restrict__ g1, const float* __restrict__ b1, const float* __restrict__ m1, const float* __restrict__ v1,
    const float* __restrict__ g2, const float* __restrict__ b2, const float* __restrict__ m2, const float* __restrict__ v2,
    const float* __restrict__ g3, const float* __restrict__ b3, const float* __restrict__ m3, const float* __restrict__ v3,
    const float* __restrict__ w3d, const float* __restrict__ b3d,
    const float* __restrict__ w5d, const float* __restrict__ b5d,
    const float* __restrict__ w7d, const float* __restrict__ b7d,
    const float* __restrict__ w9d, const float* __restrict__ b9d,
    ushort_t* __restrict__ w1b, ushort_t* __restrict__ w2b, ushort_t* __restrict__ w3b,
    float* __restrict__ WcP, float* __restrict__ biasc,
    float* __restrict__ sc1, float* __restrict__ sh1,
    float* __restrict__ sc2, float* __restrict__ sh2,
    float* __restrict__ sc3, float* __restrict__ sh3)
{
    int c = blockIdx.x, t = threadIdx.x;
    w1b[c * 256 + t] = f2bf(pre_w[c * 256 + t]);
    w2b[c * 256 + t] = f2bf(pw_w[c * 256 + t]);
    w3b[c * 256 + t] = f2bf(post_w[c * 256 + t]);
    if (t < 128) {
        float val = 0.f;
        int dy = -1, dx = 0;
        if (t < 45) { dy = t / 9; dx = t % 9; }
        else if (t >= 64 && t < 100) { int i = t - 64; dy = 5 + i / 9; dx = i % 9; }
        if (dy >= 0) {
            val = w9d[c * 81 + dy * 9 + dx];
            if (dy >= 1 && dy <= 7 && dx >= 1 && dx <= 7) val += w7d[c * 49 + (dy - 1) * 7 + (dx - 1)];
            if (dy >= 2 && dy <= 6 && dx >= 2 && dx <= 6) val += w5d[c * 25 + (dy - 2) * 5 + (dx - 2)];
            if (dy >= 3 && dy <= 5 && dx >= 3 && dx <= 5) val += w3d[c * 9 + (dy - 3) * 3 + (dx - 3)];
            if (dy == 4 && dx == 4) val += 1.0f;  // identity branch
        }
        WcP[c * 128 + t] = val;
    }
    if (t == 128) { float s = g1[c] * rsqrtf(v1[c] + 1e-5f); sc1[c] = s; sh1[c] = b1[c] - m1[c] * s; }
    if (t == 129) { float s = g2[c] * rsqrtf(v2[c] + 1e-5f); sc2[c] = s; sh2[c] = b2[c] - m2[c] * s; }
    if (t == 130) { float s = g3[c] * rsqrtf(v3[c] + 1e-5f); sc3[c] = s; sh3[c] = b3[c] - m3[c] * s; }
    if (t == 131) biasc[c] = b3d[c] + b5d[c] + b7d[c] + b9d[c];
}

// ---------------------------------------------------------------------------
// Transpose [b][64c x 64p] tile of NCHW (T = float|ushort bf16) -> [p][c] bf16.
template <typename T>
__global__ __launch_bounds__(256) void transpose_kernel(
    const T* __restrict__ in,      // [16][256][4096]
    ushort_t* __restrict__ out)    // [65536][256] bf16
{
    const int p0 = blockIdx.x * 64, c0 = blockIdx.y * 64, b = blockIdx.z;
    __shared__ ushort_t tile[64 * 72];   // [px][c], stride 72
    const int tid = threadIdx.x;
    const int c = tid >> 2, q = tid & 3;
    const T* src = in + ((size_t)b * CCH + c0 + c) * HW + p0;
#pragma unroll
    for (int j = 0; j < 4; j++) {
        const int px = 4 * q + 16 * j;
        if constexpr (__is_same(T, float)) {
            float4 v = *(const float4*)(src + px);
            tile[(px + 0) * 72 + c] = f2bf(v.x);
            tile[(px + 1) * 72 + c] = f2bf(v.y);
            tile[(px + 2) * 72 + c] = f2bf(v.z);
            tile[(px + 3) * 72 + c] = f2bf(v.w);
        } else {
            ushort4 v = *(const ushort4*)(src + px);
            tile[(px + 0) * 72 + c] = v.x;
            tile[(px + 1) * 72 + c] = v.y;
            tile[(px + 2) * 72 + c] = v.z;
            tile[(px + 3) * 72 + c] = v.w;
        }
    }
    __syncthreads();
    const int px = tid >> 2, cq = tid & 3;
    uint4 r0 = *(const uint4*)&tile[px * 72 + cq * 16];
    uint4 r1 = *(const uint4*)&tile[px * 72 + cq * 16 + 8];
    ushort_t* dst = out + ((size_t)(b * HW + p0 + px)) * CCH + c0 + cq * 16;
    *(uint4*)dst = r0;
    *(uint4*)(dst + 8) = r1;
}

// ---------------------------------------------------------------------------
// Streaming MFMA 1x1 conv + BN + ReLU. No LDS, no barriers.
// A[m][k], B[n][k], both rows k-contiguous bf16 (stride 256).
// MODE 0: A=weights, n=px, out bf16 [b][c][hw]   (conv1 -> h)
// MODE 1: A=weights, n=px, out fp32 [b][c][hw]   (conv3 -> final)
// MODE 2: A=acts,    n=cout, out bf16 [p][c]     (conv2 -> t)
template <int MODE>
__global__ __launch_bounds__(256, 2) void conv_stream(
    const ushort_t* __restrict__ A, const ushort_t* __restrict__ B,
    const float* __restrict__ sc, const float* __restrict__ sh,
    void* __restrict__ outp)
{
    int mblk, nblk;
    if (MODE == 2) { nblk = blockIdx.x; mblk = blockIdx.y; }
    else           { mblk = blockIdx.x; nblk = blockIdx.y; }
    const int tid = threadIdx.x, wave = tid >> 6, lane = tid & 63;
    const int quad = lane >> 4, L = lane & 15;
    const int wm = (wave >> 1) * 64, wn = (wave & 1) * 64;

    size_t aoff[4], boff[4];
#pragma unroll
    for (int mt = 0; mt < 4; mt++)
        aoff[mt] = (size_t)(mblk * 128 + wm + mt * 16 + L) * CCH + quad * 8;
#pragma unroll
    for (int nt = 0; nt < 4; nt++)
        boff[nt] = (size_t)(nblk * 128 + wn + nt * 16 + L) * CCH + quad * 8;

    floatx4 acc[4][4];
#pragma unroll
    for (int mt = 0; mt < 4; mt++)
#pragma unroll
        for (int nt = 0; nt < 4; nt++) acc[mt][nt] = (floatx4){0.f, 0.f, 0.f, 0.f};

    short8 ac[4], bc[4], an[4], bn[4];
#pragma unroll
    for (int mt = 0; mt < 4; mt++) ac[mt] = *(const short8*)(A + aoff[mt]);
#pragma unroll
    for (int nt = 0; nt < 4; nt++) bc[nt] = *(const short8*)(B + boff[nt]);

#pragma unroll
    for (int kti = 0; kti < 8; kti++) {
        const int ktn = (kti + 1) * 32;
        if (kti < 7) {
#pragma unroll
            for (int mt = 0; mt < 4; mt++) an[mt] = *(const short8*)(A + aoff[mt] + ktn);
#pragma unroll
            for (int nt = 0; nt < 4; nt++) bn[nt] = *(const short8*)(B + boff[nt] + ktn);
        }
#pragma unroll
        for (int mt = 0; mt < 4; mt++)
#pragma unroll
            for (int nt = 0; nt < 4; nt++)
                acc[mt][nt] = __builtin_amdgcn_mfma_f32_16x16x32_bf16(
                    ac[mt], bc[nt], acc[mt][nt], 0, 0, 0);
        if (kti < 7) {
#pragma unroll
            for (int mt = 0; mt < 4; mt++) ac[mt] = an[mt];
#pragma unroll
            for (int nt = 0; nt < 4; nt++) bc[nt] = bn[nt];
        }
    }

    if (MODE == 0 || MODE == 1) {
        // n = pixel; out NCHW [b][cout][hw]
#pragma unroll
        for (int mt = 0; mt < 4; mt++) {
#pragma unroll
            for (int r = 0; r < 4; r++) {
                const int cout = mblk * 128 + wm + mt * 16 + quad * 4 + r;
                const float s = sc[cout], h0 = sh[cout];
#pragma unroll
                for (int nt = 0; nt < 4; nt++) {
                    const int px = nblk * 128 + wn + nt * 16 + L;
                    const int b = px >> 12, hw = px & 4095;
                    const size_t o = (size_t)b * BPL + (size_t)cout * HW + hw;
                    const float v = fmaxf(fmaf(acc[mt][nt][r], s, h0), 0.f);
                    if (MODE == 0) ((ushort_t*)outp)[o] = f2bf(v);
                    else           ((float*)outp)[o] = v;
                }
            }
        }
    } else {
        // n = cout; out [p][c] bf16
        float scn[4], shn[4];
#pragma unroll
        for (int nt = 0; nt < 4; nt++) {
            const int cout = nblk * 128 + wn + nt * 16 + L;
            scn[nt] = sc[cout]; shn[nt] = sh[cout];
        }
#pragma unroll
        for (int mt = 0; mt < 4; mt++) {
#pragma unroll
            for (int r = 0; r < 4; r++) {
                const int px = mblk * 128 + wm + mt * 16 + quad * 4 + r;
#pragma unroll
                for (int nt = 0; nt < 4; nt++) {
                    const int cout = nblk * 128 + wn + nt * 16 + L;
                    const float v = fmaxf(fmaf(acc[mt][nt][r], scn[nt], shn[nt]), 0.f);
                    ((ushort_t*)outp)[(size_t)px * CCH + cout] = f2bf(v);
                }
            }
        }
    }
}

// ---------------------------------------------------------------------------
// Combined 9x9 depthwise (+identity, +summed bias), bf16 [b][c][hw] in/out.
// One block per plane; 72x72 fp32 LDS tile; 2 weight chunks (dy 0..4 / 5..8)
// to keep VGPRs ~<100.
__global__ __launch_bounds__(256, 4) void dw_kernel(
    const ushort_t* __restrict__ h, const float* __restrict__ WcP,
    const float* __restrict__ biasc, ushort_t* __restrict__ out)
{
    const int bcp = blockIdx.x, c = bcp & 255;
    const size_t plane = (size_t)bcp * HW;
    __shared__ float tile[72 * 72];
    const int tid = threadIdx.x;

    // zero halo borders (272 float4 regions, disjoint from interior rows 4..67)
    for (int f = tid; f < 272; f += 256) {
        int row, col4;
        if (f < 144) { int r = f / 18; row = (r < 4) ? r : r + 64; col4 = (f % 18) * 4; }
        else { int f2 = f - 144; row = 4 + (f2 >> 1); col4 = (f2 & 1) ? 68 : 0; }
        *(float4*)&tile[row * 72 + col4] = (float4){0.f, 0.f, 0.f, 0.f};
    }
    // interior: row r, 16 px per thread (two 16B loads)
    {
        const int r = tid >> 2, q = tid & 3;
        const ushort_t* src = h + plane + r * 64 + q * 8;
        ushort_t v0[8], v1[8];
        *(uint4*)v0 = *(const uint4*)src;
        *(uint4*)v1 = *(const uint4*)(src + 32);
        float* drow = &tile[(r + 4) * 72 + 4 + q * 8];
        float4 t0, t1;
        t0.x = bf2f(v0[0]); t0.y = bf2f(v0[1]); t0.z = bf2f(v0[2]); t0.w = bf2f(v0[3]);
        t1.x = bf2f(v0[4]); t1.y = bf2f(v0[5]); t1.z = bf2f(v0[6]); t1.w = bf2f(v0[7]);
        *(float4*)&drow[0] = t0; *(float4*)&drow[4] = t1;
        t0.x = bf2f(v1[0]); t0.y = bf2f(v1[1]); t0.z = bf2f(v1[2]); t0.w = bf2f(v1[3]);
        t1.x = bf2f(v1[4]); t1.y = bf2f(v1[5]); t1.z = bf2f(v1[6]); t1.w = bf2f(v1[7]);
        *(float4*)&drow[32] = t0; *(float4*)&drow[36] = t1;
    }
    __syncthreads();

    const int tx = tid & 15, ty = tid >> 4;
    const int x0 = tx * 4, y0 = ty * 4;
    float acc[4][4];
#pragma unroll
    for (int i = 0; i < 4; i++)
#pragma unroll
        for (int j = 0; j < 4; j++) acc[i][j] = 0.f;

    const float* wp = WcP + c * 128;
    float wr[48];

    // chunk A: dy 0..4 (45 weights), rows y0+0..7
#pragma unroll
    for (int i = 0; i < 12; i++) *(float4*)&wr[4 * i] = *(const float4*)(wp + 4 * i);
#pragma unroll
    for (int r6 = 0; r6 < 8; r6++) {
        const float* row = &tile[(y0 + r6) * 72 + x0];
        float win[12];
        *(float4*)&win[0] = *(const float4*)&row[0];
        *(float4*)&win[4] = *(const float4*)&row[4];
        *(float4*)&win[8] = *(const float4*)&row[8];
#pragma unroll
        for (int yy = 0; yy < 4; yy++) {
            const int d = r6 - yy;
            if (d >= 0 && d <= 4) {
#pragma unroll
                for (int t = 0; t < 9; t++)
#pragma unroll
                    for (int j = 0; j < 4; j++)
                        acc[yy][j] = fmaf(wr[d * 9 + t], win[j + t], acc[yy][j]);
            }
        }
    }
    // chunk B: dy 5..8 (36 weights), rows y0+5..11
#pragma unroll
    for (int i = 0; i < 9; i++) *(float4*)&wr[4 * i] = *(const float4*)(wp + 64 + 4 * i);
#pragma unroll
    for (int r6 = 5; r6 < 12; r6++) {
        const float* row = &tile[(y0 + r6) * 72 + x0];
        float win[12];
        *(float4*)&win[0] = *(const float4*)&row[0];
        *(float4*)&win[4] = *(const float4*)&row[4];
        *(float4*)&win[8] = *(const float4*)&row[8];
#pragma unroll
        for (int yy = 0; yy < 4; yy++) {
            const int d = r6 - yy;
            if (d >= 5 && d <= 8) {
#pragma unroll
                for (int t = 0; t < 9; t++)
#pragma unroll
                    for (int j = 0; j < 4; j++)
                        acc[yy][j] = fmaf(wr[(d - 5) * 9 + t], win[j + t], acc[yy][j]);
            }
        }
    }

    const float bb = biasc[c];
#pragma unroll
    for (int yy = 0; yy < 4; yy++) {
        ushort4 o;
        o.x = f2bf(acc[yy][0] + bb);
        o.y = f2bf(acc[yy][1] + bb);
        o.z = f2bf(acc[yy][2] + bb);
        o.w = f2bf(acc[yy][3] + bb);
        *(ushort4*)&out[plane + (size_t)(y0 + yy) * 64 + x0] = o;
    }
}

// ---------------------------------------------------------------------------
extern "C" void kernel_launch(void* const* d_in, const int* in_sizes, int n_in,
                              void* d_out, int out_size, void* d_ws, size_t ws_size,
                              hipStream_t stream) {
    const float* x     = (const float*)d_in[0];
    const float* pre_w = (const float*)d_in[1];
    const float* bn1g  = (const float*)d_in[2];
    const float* bn1b  = (const float*)d_in[3];
    const float* bn1m  = (const float*)d_in[4];
    const float* bn1v  = (const float*)d_in[5];
    const float* dw3w  = (const float*)d_in[6];
    const float* dw3b  = (const float*)d_in[7];
    const float* dw5w  = (const float*)d_in[8];
    const float* dw5b  = (const float*)d_in[9];
    const float* dw7w  = (const float*)d_in[10];
    const float* dw7b  = (const float*)d_in[11];
    const float* dw9w  = (const float*)d_in[12];
    const float* dw9b  = (const float*)d_in[13];
    const float* pww   = (const float*)d_in[14];
    const float* bn2g  = (const float*)d_in[15];
    const float* bn2b  = (const float*)d_in[16];
    const float* bn2m  = (const float*)d_in[17];
    const float* bn2v  = (const float*)d_in[18];
    const float* postw = (const float*)d_in[19];
    const float* bn3g  = (const float*)d_in[20];
    const float* bn3b  = (const float*)d_in[21];
    const float* bn3m  = (const float*)d_in[22];
    const float* bn3v  = (const float*)d_in[23];

    // Buffer map (32 MB slots):
    //   ws0 = ws[0:32M]    : xT -> (dead) -> s -> (dead) -> t
    //   do0 = d_out[0:32M] : h
    //   do1 = d_out[32:64M]: sT
    //   aux = ws + 32M     : weights etc (~0.53 MB)
    char* wsb = (char*)d_ws;
    ushort_t* ws0 = (ushort_t*)wsb;
    ushort_t* do0 = (ushort_t*)d_out;
    ushort_t* do1 = (ushort_t*)((char*)d_out + (size_t)32 * 1024 * 1024);
    char* aux = wsb + (size_t)32 * 1024 * 1024;
    ushort_t* w1b = (ushort_t*)aux;
    ushort_t* w2b = w1b + 65536;
    ushort_t* w3b = w2b + 65536;
    float* WcP   = (float*)(w3b + 65536);      // 256*128 fp32
    float* biasc = WcP + 256 * 128;
    float* sc1 = biasc + 256;  float* sh1 = sc1 + 256;
    float* sc2 = sh1 + 256;    float* sh2 = sc2 + 256;
    float* sc3 = sh2 + 256;    float* sh3 = sc3 + 256;

    prep_kernel<<<256, 256, 0, stream>>>(
        pre_w, pww, postw,
        bn1g, bn1b, bn1m, bn1v, bn2g, bn2b, bn2m, bn2v, bn3g, bn3b, bn3m, bn3v,
        dw3w, dw3b, dw5w, dw5b, dw7w, dw7b, dw9w, dw9b,
        w1b, w2b, w3b, WcP, biasc, sc1, sh1, sc2, sh2, sc3, sh3);

    dim3 tg(64, 4, 16);
    // xT = transpose(x) fp32->bf16 [p][c]
    transpose_kernel<float><<<tg, 256, 0, stream>>>(x, ws0);
    // h = relu(bn1(pre_w · x))  : A=w1b, B=xT -> bf16 [b][c][hw] in do0
    conv_stream<0><<<dim3(2, 512), 256, 0, stream>>>(w1b, ws0, sc1, sh1, do0);
    // s = dw9(h) + bias : do0 -> ws0 (xT dead)
    dw_kernel<<<16 * CCH, 256, 0, stream>>>(do0, WcP, biasc, ws0);
    // sT = transpose(s) bf16 [p][c] -> do1
    transpose_kernel<ushort_t><<<tg, 256, 0, stream>>>(ws0, do1);
    // t = relu(bn2(pw_w · s)) : A=sT(acts), B=w2b -> bf16 [p][c] in ws0 (s dead)
    conv_stream<2><<<dim3(2, 512), 256, 0, stream>>>(do1, w2b, sc2, sh2, ws0);
    // out = relu(bn3(post_w · t)) : A=w3b, B=t -> fp32 [b][c][hw] full d_out
    conv_stream<1><<<dim3(2, 512), 256, 0, stream>>>(w3b, ws0, sc3, sh3, (float*)d_out);
}

// Round 5
// 244.105 us; speedup vs baseline: 2.1448x; 1.6347x over previous
//
#include <hip/hip_runtime.h>
#include <stdint.h>

#define HW 4096
#define CCH 256
#define BPL (CCH * HW)          // per-batch plane elems
#define LSTR 264                // LDS Bs row stride in shorts (256+8 pad; 528B = 16B-aligned)

typedef __attribute__((ext_vector_type(8))) short short8;
typedef __attribute__((ext_vector_type(4))) float floatx4;
typedef unsigned short ushort_t;

__device__ inline ushort_t f2bf(float f) {
    union { float f; unsigned int u; } v; v.f = f;
    unsigned int r = v.u + 0x7FFFu + ((v.u >> 16) & 1u);   // RNE
    return (ushort_t)(r >> 16);
}
__device__ inline float bf2f(ushort_t u) {
    union { unsigned int u; float f; } v; v.u = ((unsigned int)u) << 16;
    return v.f;
}

// ---------------------------------------------------------------------------
// prep: weights->bf16, combined dw 9x9 (chunked layout), folded BN params.
// WcP[c][128]: slots 0..44 = dy 0..4 (dy*9+dx), slots 64..99 = dy 5..8.
__global__ void prep_kernel(
    const float* __restrict__ pre_w, const float* __restrict__ pw_w, const float* __restrict__ post_w,
    const float* __restrict__ g1, const float* __restrict__ b1, const float* __restrict__ m1, const float* __restrict__ v1,
    const float* __restrict__ g2, const float* __restrict__ b2, const float* __restrict__ m2, const float* __restrict__ v2,
    const float* __restrict__ g3, const float* __restrict__ b3, const float* __restrict__ m3, const float* __restrict__ v3,
    const float* __restrict__ w3d, const float* __restrict__ b3d,
    const float* __restrict__ w5d, const float* __restrict__ b5d,
    const float* __restrict__ w7d, const float* __restrict__ b7d,
    const float* __restrict__ w9d, const float* __restrict__ b9d,
    ushort_t* __restrict__ w1b, ushort_t* __restrict__ w2b, ushort_t* __restrict__ w3b,
    float* __restrict__ WcP, float* __restrict__ biasc,
    float* __restrict__ sc1, float* __restrict__ sh1,
    float* __restrict__ sc2, float* __restrict__ sh2,
    float* __restrict__ sc3, float* __restrict__ sh3)
{
    int c = blockIdx.x, t = threadIdx.x;
    w1b[c * 256 + t] = f2bf(pre_w[c * 256 + t]);
    w2b[c * 256 + t] = f2bf(pw_w[c * 256 + t]);
    w3b[c * 256 + t] = f2bf(post_w[c * 256 + t]);
    if (t < 128) {
        float val = 0.f;
        int dy = -1, dx = 0;
        if (t < 45) { dy = t / 9; dx = t % 9; }
        else if (t >= 64 && t < 100) { int i = t - 64; dy = 5 + i / 9; dx = i % 9; }
        if (dy >= 0) {
            val = w9d[c * 81 + dy * 9 + dx];
            if (dy >= 1 && dy <= 7 && dx >= 1 && dx <= 7) val += w7d[c * 49 + (dy - 1) * 7 + (dx - 1)];
            if (dy >= 2 && dy <= 6 && dx >= 2 && dx <= 6) val += w5d[c * 25 + (dy - 2) * 5 + (dx - 2)];
            if (dy >= 3 && dy <= 5 && dx >= 3 && dx <= 5) val += w3d[c * 9 + (dy - 3) * 3 + (dx - 3)];
            if (dy == 4 && dx == 4) val += 1.0f;  // identity branch
        }
        WcP[c * 128 + t] = val;
    }
    if (t == 128) { float s = g1[c] * rsqrtf(v1[c] + 1e-5f); sc1[c] = s; sh1[c] = b1[c] - m1[c] * s; }
    if (t == 129) { float s = g2[c] * rsqrtf(v2[c] + 1e-5f); sc2[c] = s; sh2[c] = b2[c] - m2[c] * s; }
    if (t == 130) { float s = g3[c] * rsqrtf(v3[c] + 1e-5f); sc3[c] = s; sh3[c] = b3[c] - m3[c] * s; }
    if (t == 131) biasc[c] = b3d[c] + b5d[c] + b7d[c] + b9d[c];
}

// ---------------------------------------------------------------------------
// LDS-staged MFMA 1x1 conv(s) on a 128-px tile, all 256 cout, K=256.
// Staging transposes the NCHW input tile into Bs[px][ch] bf16 (fuses the
// transpose kernels). Wave w computes cout 64w..64w+63 (4 m-tiles x 8 n-tiles).
// MODE 0: in fp32 NCHW -> GEMM(wA)+bnA+relu -> bf16 NCHW       (conv1)
// MODE 1: in bf16 NCHW -> GEMM(wA)+bnA+relu -> t in LDS ->
//         GEMM(wB)+bnB+relu -> fp32 NCHW                       (conv2+conv3)
template <int MODE>
__global__ __launch_bounds__(256, 2) void conv_tile(
    const void* __restrict__ inp,
    const ushort_t* __restrict__ wA, const float* __restrict__ scA, const float* __restrict__ shA,
    const ushort_t* __restrict__ wB, const float* __restrict__ scB, const float* __restrict__ shB,
    void* __restrict__ outp)
{
    __shared__ __align__(16) ushort_t Bs[128 * LSTR];   // 67.6 KB
    const int tid = threadIdx.x;
    const int P0 = blockIdx.x * 128;          // global pixel base (never crosses batch)
    const int b = P0 >> 12, hw0 = P0 & 4095;
    unsigned int* Bsd = (unsigned int*)Bs;

    // ---- stage input tile [256 ch][128 px] -> Bs[px][ch] (ch-pairs packed as dwords)
    {
        const int c2 = tid & 127, ph = tid >> 7, px0 = ph * 64;
        if (MODE == 0) {
            const float* s0 = (const float*)inp + (size_t)b * BPL + (size_t)(2 * c2) * HW + hw0 + px0;
            const float* s1 = s0 + HW;
#pragma unroll
            for (int i = 0; i < 16; i++) {
                float4 v0 = *(const float4*)(s0 + 4 * i);
                float4 v1 = *(const float4*)(s1 + 4 * i);
                const int px = px0 + 4 * i;
                Bsd[(px + 0) * (LSTR / 2) + c2] = (unsigned)f2bf(v0.x) | ((unsigned)f2bf(v1.x) << 16);
                Bsd[(px + 1) * (LSTR / 2) + c2] = (unsigned)f2bf(v0.y) | ((unsigned)f2bf(v1.y) << 16);
                Bsd[(px + 2) * (LSTR / 2) + c2] = (unsigned)f2bf(v0.z) | ((unsigned)f2bf(v1.z) << 16);
                Bsd[(px + 3) * (LSTR / 2) + c2] = (unsigned)f2bf(v0.w) | ((unsigned)f2bf(v1.w) << 16);
            }
        } else {
            const ushort_t* s0 = (const ushort_t*)inp + (size_t)b * BPL + (size_t)(2 * c2) * HW + hw0 + px0;
            const ushort_t* s1 = s0 + HW;
#pragma unroll
            for (int i = 0; i < 8; i++) {
                union { uint4 v; ushort_t u[8]; } r0, r1;
                r0.v = *(const uint4*)(s0 + 8 * i);
                r1.v = *(const uint4*)(s1 + 8 * i);
                const int px = px0 + 8 * i;
#pragma unroll
                for (int j = 0; j < 8; j++)
                    Bsd[(px + j) * (LSTR / 2) + c2] = (unsigned)r0.u[j] | ((unsigned)r1.u[j] << 16);
            }
        }
    }
    __syncthreads();

    const int wave = tid >> 6, lane = tid & 63, quad = lane >> 4, L = lane & 15;
    const int coutw = wave * 64;

    floatx4 acc[4][8];

    // GEMM over K=256 (8 chunks of 32): A from global (L2-hot weights,
    // prefetched one chunk ahead), B from LDS.
    auto run_gemm = [&](const ushort_t* W) {
#pragma unroll
        for (int mt = 0; mt < 4; mt++)
#pragma unroll
            for (int nt = 0; nt < 8; nt++) acc[mt][nt] = (floatx4){0.f, 0.f, 0.f, 0.f};
        const ushort_t* Ab = W + (size_t)(coutw + L) * CCH + quad * 8;
        short8 Ac[4], An[4];
#pragma unroll
        for (int mt = 0; mt < 4; mt++) Ac[mt] = *(const short8*)(Ab + mt * 16 * CCH);
#pragma unroll
        for (int kt = 0; kt < 8; kt++) {
            if (kt < 7) {
#pragma unroll
                for (int mt = 0; mt < 4; mt++)
                    An[mt] = *(const short8*)(Ab + mt * 16 * CCH + (kt + 1) * 32);
            }
            short8 Bf[8];
#pragma unroll
            for (int nt = 0; nt < 8; nt++)
                Bf[nt] = *(const short8*)&Bs[(nt * 16 + L) * LSTR + kt * 32 + quad * 8];
#pragma unroll
            for (int mt = 0; mt < 4; mt++)
#pragma unroll
                for (int nt = 0; nt < 8; nt++)
                    acc[mt][nt] = __builtin_amdgcn_mfma_f32_16x16x32_bf16(
                        Ac[mt], Bf[nt], acc[mt][nt], 0, 0, 0);
            if (kt < 7) {
#pragma unroll
                for (int mt = 0; mt < 4; mt++) Ac[mt] = An[mt];
            }
        }
    };

    run_gemm(wA);

    if (MODE == 0) {
        // epilogue: bnA + relu -> bf16 NCHW
        ushort_t* outb = (ushort_t*)outp + (size_t)b * BPL + hw0;
#pragma unroll
        for (int mt = 0; mt < 4; mt++) {
#pragma unroll
            for (int r = 0; r < 4; r++) {
                const int cout = coutw + mt * 16 + quad * 4 + r;
                const float s = scA[cout], h0 = shA[cout];
#pragma unroll
                for (int nt = 0; nt < 8; nt++)
                    outb[(size_t)cout * HW + nt * 16 + L] =
                        f2bf(fmaxf(fmaf(acc[mt][nt][r], s, h0), 0.f));
            }
        }
    } else {
        // t = relu(bnA(.)) -> back into Bs (in-place; s fully consumed)
        __syncthreads();
#pragma unroll
        for (int mt = 0; mt < 4; mt++) {
            const int cout0 = coutw + mt * 16 + quad * 4;
            float sc4[4], sh4[4];
#pragma unroll
            for (int r = 0; r < 4; r++) { sc4[r] = scA[cout0 + r]; sh4[r] = shA[cout0 + r]; }
#pragma unroll
            for (int nt = 0; nt < 8; nt++) {
                const int px = nt * 16 + L;
                ushort4 pk;
                pk.x = f2bf(fmaxf(fmaf(acc[mt][nt][0], sc4[0], sh4[0]), 0.f));
                pk.y = f2bf(fmaxf(fmaf(acc[mt][nt][1], sc4[1], sh4[1]), 0.f));
                pk.z = f2bf(fmaxf(fmaf(acc[mt][nt][2], sc4[2], sh4[2]), 0.f));
                pk.w = f2bf(fmaxf(fmaf(acc[mt][nt][3], sc4[3], sh4[3]), 0.f));
                *(ushort4*)&Bs[px * LSTR + cout0] = pk;
            }
        }
        __syncthreads();
        run_gemm(wB);
        // epilogue: bnB + relu -> fp32 NCHW
        float* outb = (float*)outp + (size_t)b * BPL + hw0;
#pragma unroll
        for (int mt = 0; mt < 4; mt++) {
#pragma unroll
            for (int r = 0; r < 4; r++) {
                const int cout = coutw + mt * 16 + quad * 4 + r;
                const float s = scB[cout], h0 = shB[cout];
#pragma unroll
                for (int nt = 0; nt < 8; nt++)
                    outb[(size_t)cout * HW + nt * 16 + L] =
                        fmaxf(fmaf(acc[mt][nt][r], s, h0), 0.f);
            }
        }
    }
}

// ---------------------------------------------------------------------------
// Combined 9x9 depthwise (+identity, +summed bias), bf16 NCHW in/out.
// One block per (b,c) plane; 72x72 fp32 LDS tile; 2 weight chunks.
// launch_bounds min-waves=3 -> VGPR cap ~170: NO SPILLS (R4's (256,4) spilled).
__global__ __launch_bounds__(256, 3) void dw_kernel(
    const ushort_t* __restrict__ h, const float* __restrict__ WcP,
    const float* __restrict__ biasc, ushort_t* __restrict__ out)
{
    const int bcp = blockIdx.x, c = bcp & 255;
    const size_t plane = (size_t)bcp * HW;
    __shared__ float tile[72 * 72];
    const int tid = threadIdx.x;

    // zero halo borders (272 float4 regions, disjoint from interior rows 4..67)
    for (int f = tid; f < 272; f += 256) {
        int row, col4;
        if (f < 144) { int r = f / 18; row = (r < 4) ? r : r + 64; col4 = (f % 18) * 4; }
        else { int f2 = f - 144; row = 4 + (f2 >> 1); col4 = (f2 & 1) ? 68 : 0; }
        *(float4*)&tile[row * 72 + col4] = (float4){0.f, 0.f, 0.f, 0.f};
    }
    // interior: thread loads 32 contiguous bytes (16 px) of row r
    {
        const int r = tid >> 2, q = tid & 3;
        const ushort_t* src = h + plane + r * 64 + q * 16;
        union { uint4 v; ushort_t u[8]; } a, bq;
        a.v  = *(const uint4*)src;
        bq.v = *(const uint4*)(src + 8);
        float* drow = &tile[(r + 4) * 72 + 4 + q * 16];
        float4 t0, t1;
        t0.x = bf2f(a.u[0]); t0.y = bf2f(a.u[1]); t0.z = bf2f(a.u[2]); t0.w = bf2f(a.u[3]);
        t1.x = bf2f(a.u[4]); t1.y = bf2f(a.u[5]); t1.z = bf2f(a.u[6]); t1.w = bf2f(a.u[7]);
        *(float4*)&drow[0] = t0; *(float4*)&drow[4] = t1;
        t0.x = bf2f(bq.u[0]); t0.y = bf2f(bq.u[1]); t0.z = bf2f(bq.u[2]); t0.w = bf2f(bq.u[3]);
        t1.x = bf2f(bq.u[4]); t1.y = bf2f(bq.u[5]); t1.z = bf2f(bq.u[6]); t1.w = bf2f(bq.u[7]);
        *(float4*)&drow[8] = t0; *(float4*)&drow[12] = t1;
    }
    __syncthreads();

    const int tx = tid & 15, ty = tid >> 4;
    const int x0 = tx * 4, y0 = ty * 4;
    float acc[4][4];
#pragma unroll
    for (int i = 0; i < 4; i++)
#pragma unroll
        for (int j = 0; j < 4; j++) acc[i][j] = 0.f;

    const float* wp = WcP + c * 128;
    float wr[48];

    // chunk A: dy 0..4 (45 weights), rows y0+0..7
#pragma unroll
    for (int i = 0; i < 12; i++) *(float4*)&wr[4 * i] = *(const float4*)(wp + 4 * i);
#pragma unroll
    for (int r6 = 0; r6 < 8; r6++) {
        const float* row = &tile[(y0 + r6) * 72 + x0];
        float win[12];
        *(float4*)&win[0] = *(const float4*)&row[0];
        *(float4*)&win[4] = *(const float4*)&row[4];
        *(float4*)&win[8] = *(const float4*)&row[8];
#pragma unroll
        for (int yy = 0; yy < 4; yy++) {
            const int d = r6 - yy;
            if (d >= 0 && d <= 4) {
#pragma unroll
                for (int t = 0; t < 9; t++)
#pragma unroll
                    for (int j = 0; j < 4; j++)
                        acc[yy][j] = fmaf(wr[d * 9 + t], win[j + t], acc[yy][j]);
            }
        }
    }
    // chunk B: dy 5..8 (36 weights), rows y0+5..11
#pragma unroll
    for (int i = 0; i < 9; i++) *(float4*)&wr[4 * i] = *(const float4*)(wp + 64 + 4 * i);
#pragma unroll
    for (int r6 = 5; r6 < 12; r6++) {
        const float* row = &tile[(y0 + r6) * 72 + x0];
        float win[12];
        *(float4*)&win[0] = *(const float4*)&row[0];
        *(float4*)&win[4] = *(const float4*)&row[4];
        *(float4*)&win[8] = *(const float4*)&row[8];
#pragma unroll
        for (int yy = 0; yy < 4; yy++) {
            const int d = r6 - yy;
            if (d >= 5 && d <= 8) {
#pragma unroll
                for (int t = 0; t < 9; t++)
#pragma unroll
                    for (int j = 0; j < 4; j++)
                        acc[yy][j] = fmaf(wr[(d - 5) * 9 + t], win[j + t], acc[yy][j]);
            }
        }
    }

    const float bb = biasc[c];
#pragma unroll
    for (int yy = 0; yy < 4; yy++) {
        ushort4 o;
        o.x = f2bf(acc[yy][0] + bb);
        o.y = f2bf(acc[yy][1] + bb);
        o.z = f2bf(acc[yy][2] + bb);
        o.w = f2bf(acc[yy][3] + bb);
        *(ushort4*)&out[plane + (size_t)(y0 + yy) * 64 + x0] = o;
    }
}

// ---------------------------------------------------------------------------
extern "C" void kernel_launch(void* const* d_in, const int* in_sizes, int n_in,
                              void* d_out, int out_size, void* d_ws, size_t ws_size,
                              hipStream_t stream) {
    const float* x     = (const float*)d_in[0];
    const float* pre_w = (const float*)d_in[1];
    const float* bn1g  = (const float*)d_in[2];
    const float* bn1b  = (const float*)d_in[3];
    const float* bn1m  = (const float*)d_in[4];
    const float* bn1v  = (const float*)d_in[5];
    const float* dw3w  = (const float*)d_in[6];
    const float* dw3b  = (const float*)d_in[7];
    const float* dw5w  = (const float*)d_in[8];
    const float* dw5b  = (const float*)d_in[9];
    const float* dw7w  = (const float*)d_in[10];
    const float* dw7b  = (const float*)d_in[11];
    const float* dw9w  = (const float*)d_in[12];
    const float* dw9b  = (const float*)d_in[13];
    const float* pww   = (const float*)d_in[14];
    const float* bn2g  = (const float*)d_in[15];
    const float* bn2b  = (const float*)d_in[16];
    const float* bn2m  = (const float*)d_in[17];
    const float* bn2v  = (const float*)d_in[18];
    const float* postw = (const float*)d_in[19];
    const float* bn3g  = (const float*)d_in[20];
    const float* bn3b  = (const float*)d_in[21];
    const float* bn3m  = (const float*)d_in[22];
    const float* bn3v  = (const float*)d_in[23];

    // Buffers:
    //   h (bf16, 32 MiB)  -> d_out storage (dead before final fp32 write)
    //   s (bf16, 32 MiB)  -> ws[0:32Mi]
    //   aux               -> ws + 33 MiB
    char* wsb = (char*)d_ws;
    ushort_t* sbuf = (ushort_t*)wsb;
    ushort_t* hbuf = (ushort_t*)d_out;
    char* aux = wsb + (size_t)33 * 1024 * 1024;
    ushort_t* w1b = (ushort_t*)aux;
    ushort_t* w2b = w1b + 65536;
    ushort_t* w3b = w2b + 65536;
    float* WcP   = (float*)(w3b + 65536);      // 256*128 fp32
    float* biasc = WcP + 256 * 128;
    float* sc1 = biasc + 256;  float* sh1 = sc1 + 256;
    float* sc2 = sh1 + 256;    float* sh2 = sc2 + 256;
    float* sc3 = sh2 + 256;    float* sh3 = sc3 + 256;

    prep_kernel<<<256, 256, 0, stream>>>(
        pre_w, pww, postw,
        bn1g, bn1b, bn1m, bn1v, bn2g, bn2b, bn2m, bn2v, bn3g, bn3b, bn3m, bn3v,
        dw3w, dw3b, dw5w, dw5b, dw7w, dw7b, dw9w, dw9b,
        w1b, w2b, w3b, WcP, biasc, sc1, sh1, sc2, sh2, sc3, sh3);

    // conv1: x fp32 -> h bf16 NCHW (in d_out storage)
    conv_tile<0><<<512, 256, 0, stream>>>(x, w1b, sc1, sh1,
                                          nullptr, nullptr, nullptr, hbuf);
    // dw: h -> s bf16 NCHW (in ws)
    dw_kernel<<<16 * CCH, 256, 0, stream>>>(hbuf, WcP, biasc, sbuf);
    // conv2+conv3 fused: s -> out fp32 NCHW (d_out; h dead)
    conv_tile<1><<<512, 256, 0, stream>>>(sbuf, w2b, sc2, sh2,
                                          w3b, sc3, sh3, (float*)d_out);
}